// Round 15
// baseline (111.936 us; speedup 1.0000x reference)
//
#include <hip/hip_runtime.h>
#include <cstdint>
#include <cstddef>

#define MTOT 16384      // B*S
#define MPAD 16388      // + 4 zero pad rows
#define INCH 512        // W*E
#define NF   256        // filters per conv
#define PREPB 6144      // prep blocks (2048 per conv)

typedef __attribute__((ext_vector_type(4))) float f32x4;
typedef __attribute__((ext_vector_type(8))) short bf16x8;

__device__ __forceinline__ short f2bf(float f) {
    union { float f; unsigned u; } v; v.f = f;
    unsigned r = v.u + 0x7FFFu + ((v.u >> 16) & 1u);
    return (short)(r >> 16);
}

__device__ __forceinline__ void gld16(const short* g, short* l) {
    __builtin_amdgcn_global_load_lds(
        (const __attribute__((address_space(1))) unsigned int*)g,
        (__attribute__((address_space(3))) unsigned int*)l,
        16, 0, 0);
}

// ---------------- 1. fused: conv-weight prep + embedding gather -------------
// Weight layout (BK=32): [kt(k>>5)][nb][128 fr][4 cc][8 klo], cc = kc^((fr>>1)&3)
__global__ void embed_prep(const float* __restrict__ x, const float* __restrict__ ew,
                           short* __restrict__ emb,
                           const float* __restrict__ w0, const float* __restrict__ w1,
                           const float* __restrict__ w2, short* __restrict__ Wtb) {
    int tid = threadIdx.x;
    if (blockIdx.x < PREPB) {
        int blk = blockIdx.x;
        int conv = blk >> 11;
        int ki = conv + 2;
        int K = 512 * ki;
        int idx = (blk & 2047) * 256 + tid;
        if (idx >= K * NF) return;
        int u = idx >> 9;
        int ic = idx & 511;
        int f = u / ki;
        int j = u - f * ki;
        const float* w = (conv == 0) ? w0 : (conv == 1) ? w1 : w2;
        float val = w[(size_t)f * K + ic * ki + j];
        int k = j * 512 + ic;
        int kt = k >> 5, kl = k & 31;
        int kc = kl >> 3, klo = kl & 7;
        int nb = f >> 7, fr = f & 127;
        int cc = kc ^ ((fr >> 1) & 3);
        size_t off = (conv == 0) ? 0 : (conv == 1) ? 262144 : 655360;
        Wtb[off + (((size_t)(kt * 2 + nb) * 128 + fr) * 4 + cc) * 8 + klo] = f2bf(val);
        return;
    }
    int m = blockIdx.x - PREPB;
    if (m >= MTOT) {
        if (tid < 64) {
            uint4 z = make_uint4(0u, 0u, 0u, 0u);
            *(uint4*)&emb[(size_t)m * INCH + tid * 8] = z;
        }
        return;
    }
    int w = tid >> 4, u = tid & 15;
    const float* xr = x + ((size_t)m * 16 + w) * 128 + u * 8;
    float4 a0 = *(const float4*)xr;
    float4 a1 = *(const float4*)(xr + 4);
    float vals[8] = {a0.x, a0.y, a0.z, a0.w, a1.x, a1.y, a1.z, a1.w};
    int myidx = 0;
#pragma unroll
    for (int jj = 0; jj < 8; ++jj)
        if (vals[jj] != 0.f) myidx = u * 8 + jj;
#pragma unroll
    for (int off = 1; off < 16; off <<= 1)
        myidx = max(myidx, __shfl_xor(myidx, off));
    if (u < 4) {
        const float* er = ew + (size_t)myidx * 32 + u * 8;
        float4 e0 = *(const float4*)er;
        float4 e1 = *(const float4*)(er + 4);
        short h[8];
        h[0] = f2bf(e0.x); h[1] = f2bf(e0.y); h[2] = f2bf(e0.z); h[3] = f2bf(e0.w);
        h[4] = f2bf(e1.x); h[5] = f2bf(e1.y); h[6] = f2bf(e1.z); h[7] = f2bf(e1.w);
        *(uint4*)&emb[(size_t)m * INCH + w * 32 + u * 8] = *(uint4*)h;
    }
}

// ---------------- 2. conv GEMM: 64x128 tile, BK=32, 4 blocks/CU -------------
// A staged once (64 rows LDS); boundary rows (R+j>63) read direct-from-global
// for the single affected fragment (wr==1,i==1). LDS 36.9KB -> 4 blocks/CU,
// 1536 blocks -> 6-deep queue: independent barrier streams + ki load balance.
__launch_bounds__(256)
__global__ void conv_gemm(const short* __restrict__ emb, const short* __restrict__ Wtb,
                          const float* __restrict__ cb0, const float* __restrict__ cb1,
                          const float* __restrict__ cb2,
                          float* __restrict__ sumP, float* __restrict__ ssqP,
                          float* __restrict__ mxF, float* __restrict__ mnF) {
    // XCD swizzle: 1536 blocks, 192/XCD; 12 consecutive logicals (2 mb64 x 6)
    // share a batch-row A panel -> same-XCD L2 reuse.
    int o = blockIdx.x;
    int logical = (o & 7) * 192 + (o >> 3);
    int mb = logical / 6;            // mb64: 0..255
    int r6 = logical - mb * 6;
    int conv = r6 >> 1;
    int nb = r6 & 1;
    int ki = conv + 2;
    int m0 = mb * 64;
    const short* Wc = Wtb + ((conv == 0) ? 0 : (conv == 1) ? 262144 : 655360);

    __shared__ __align__(16) short As[64 * 32];     // 4 KB
    __shared__ __align__(16) short Bs[4 * 4096];    // 32 KB (4 j-slices)

    int tid = threadIdx.x;
    int wv = tid >> 6, lane = tid & 63, g = lane >> 4, ln = lane & 15;
    int wr = wv >> 1, wc = wv & 1;   // per-wave out: 32 rows x 64 cols

    f32x4 acc[2][4];
#pragma unroll
    for (int i = 0; i < 2; ++i)
#pragma unroll
        for (int n = 0; n < 4; ++n) acc[i][n] = (f32x4){0.f, 0.f, 0.f, 0.f};

    // A staging: 256 chunks (64 rows x 4), 1 per thread, pre-swizzled source
    int arow0 = tid >> 2, acol0 = ((tid & 3) ^ ((arow0 >> 1) & 3)) * 8;
    int c0 = tid, c1 = 256 + tid;

    // B fragment offsets
    int bOff[4];
#pragma unroll
    for (int i = 0; i < 4; ++i) {
        int F = wc * 64 + i * 16 + ln;
        bOff[i] = F * 32 + ((g ^ ((F >> 1) & 3)) * 8);
    }
    int Rb[2];
#pragma unroll
    for (int i = 0; i < 2; ++i) Rb[i] = wr * 32 + i * 16 + ln;

    for (int ic0 = 0; ic0 < INCH; ic0 += 32) {
        int kt0 = ic0 >> 5;
        const short* abase = emb + (size_t)m0 * INCH + ic0;
        __syncthreads();                      // prior compute done: buffers free
        gld16(abase + (size_t)arow0 * INCH + acol0, As + wv * 512);
        for (int jj = 0; jj < ki; ++jj) {
            const short* Bsrc = Wc + (size_t)((jj * 16 + kt0) * 2 + nb) * 4096;
            gld16(Bsrc + c0 * 8, Bs + jj * 4096 + wv * 512);
            gld16(Bsrc + c1 * 8, Bs + jj * 4096 + 2048 + wv * 512);
        }
        __syncthreads();                      // staged data visible
        for (int jj = 0; jj < ki; ++jj) {
            bf16x8 afr[2], bfr[4];
            {
                int R0 = Rb[0] + jj;          // <= 34: always LDS
                afr[0] = *(const bf16x8*)&As[R0 * 32 + ((g ^ ((R0 >> 1) & 3)) * 8)];
            }
            if (wr == 1) {                    // rows 48+ln+jj (<=66): global direct
                afr[1] = *(const bf16x8*)&abase[(size_t)(48 + ln + jj) * INCH + g * 8];
            } else {
                int R1 = Rb[1] + jj;          // <= 34
                afr[1] = *(const bf16x8*)&As[R1 * 32 + ((g ^ ((R1 >> 1) & 3)) * 8)];
            }
#pragma unroll
            for (int i = 0; i < 4; ++i) bfr[i] = *(const bf16x8*)&Bs[jj * 4096 + bOff[i]];
#pragma unroll
            for (int mi = 0; mi < 2; ++mi)
#pragma unroll
                for (int ni = 0; ni < 4; ++ni)
                    acc[mi][ni] = __builtin_amdgcn_mfma_f32_16x16x32_bf16(afr[mi], bfr[ni], acc[mi][ni], 0, 0, 0);
        }
    }

    // epilogue: bias + per-(block,f) {sum, sumsq, max, min}
    int L = 127 - conv;
    int t0 = (mb & 1) * 64;
    const float* cbp = (conv == 0) ? cb0 : (conv == 1) ? cb1 : cb2;
    float s[4] = {0.f, 0.f, 0.f, 0.f}, q[4] = {0.f, 0.f, 0.f, 0.f};
    float mx[4], mn[4], cb[4];
#pragma unroll
    for (int ni = 0; ni < 4; ++ni) {
        mx[ni] = -3.0e38f; mn[ni] = 3.0e38f;
        cb[ni] = cbp[nb * 128 + wc * 64 + ni * 16 + ln];
    }
#pragma unroll
    for (int mi = 0; mi < 2; ++mi) {
#pragma unroll
        for (int r = 0; r < 4; ++r) {
            int t = t0 + wr * 32 + mi * 16 + g * 4 + r;
            if (t >= L) continue;
#pragma unroll
            for (int ni = 0; ni < 4; ++ni) {
                float c = acc[mi][ni][r] + cb[ni];
                s[ni] += c; q[ni] += c * c;
                mx[ni] = fmaxf(mx[ni], c); mn[ni] = fminf(mn[ni], c);
            }
        }
    }
#pragma unroll
    for (int off = 16; off < 64; off <<= 1) {
#pragma unroll
        for (int ni = 0; ni < 4; ++ni) {
            s[ni] += __shfl_xor(s[ni], off);
            q[ni] += __shfl_xor(q[ni], off);
            mx[ni] = fmaxf(mx[ni], __shfl_xor(mx[ni], off));
            mn[ni] = fminf(mn[ni], __shfl_xor(mn[ni], off));
        }
    }
    __syncthreads();
    float* sm = (float*)As;                   // [4 stats][2 wr][128 col] = 4KB
    if (g == 0) {
#pragma unroll
        for (int ni = 0; ni < 4; ++ni) {
            int col = wc * 64 + ni * 16 + ln;
            int oo = wr * 128 + col;
            sm[oo] = s[ni]; sm[256 + oo] = q[ni];
            sm[512 + oo] = mx[ni]; sm[768 + oo] = mn[ni];
        }
    }
    __syncthreads();
    if (tid < 128) {
        float S  = sm[tid] + sm[128 + tid];
        float Q  = sm[256 + tid] + sm[384 + tid];
        float MX = fmaxf(sm[512 + tid], sm[640 + tid]);
        float MN = fminf(sm[768 + tid], sm[896 + tid]);
        size_t off2 = ((size_t)(conv * 256 + mb)) * 256 + nb * 128 + tid;
        sumP[off2] = S; ssqP[off2] = Q; mxF[off2] = MX; mnF[off2] = MN;
    }
}

// ---------------- 3. BN stats only: af/df[768] (3 blocks x 1024) ------------
__global__ void bn_stats(const float* __restrict__ sumP, const float* __restrict__ ssqP,
                         const float* __restrict__ g0, const float* __restrict__ g1,
                         const float* __restrict__ g2,
                         const float* __restrict__ b0, const float* __restrict__ b1,
                         const float* __restrict__ b2,
                         float* __restrict__ af, float* __restrict__ df) {
    int conv = blockIdx.x;
    int tid = threadIdx.x;
    int part = tid >> 8, f = tid & 255;
    float s = 0.f, q = 0.f;
#pragma unroll 4
    for (int mb = part * 64; mb < part * 64 + 64; ++mb) {
        size_t o = ((size_t)(conv * 256 + mb)) * 256 + f;
        s += sumP[o]; q += ssqP[o];
    }
    __shared__ float sred[4][256], qred[4][256];
    sred[part][f] = s; qred[part][f] = q;
    __syncthreads();
    if (part == 0) {
        s = sred[0][f] + sred[1][f] + sred[2][f] + sred[3][f];
        q = qred[0][f] + qred[1][f] + qred[2][f] + qred[3][f];
        int L = 127 - conv;
        float n = 128.f * (float)L;
        float mu = s / n;
        float var = fmaxf(q / n - mu * mu, 0.f);
        const float* gp = (conv == 0) ? g0 : (conv == 1) ? g1 : g2;
        const float* bp = (conv == 0) ? b0 : (conv == 1) ? b1 : b2;
        float a = gp[f] * rsqrtf(var + 1e-5f);
        af[conv * 256 + f] = a;
        df[conv * 256 + f] = bp[f] - mu * a;
    }
}

// ---------------- 4. pool + FC1: 128 blocks x 1024 threads ------------------
__global__ void pool_fc1(const float* __restrict__ mxF, const float* __restrict__ mnF,
                         const float* __restrict__ af, const float* __restrict__ df,
                         const float* __restrict__ fc1w, const float* __restrict__ fc1b,
                         float* __restrict__ zb) {
    int b = blockIdx.x;
    int tid = threadIdx.x;
    __shared__ float pl[768];
    __shared__ float ps[8][100];
    if (tid < 768) {
        int conv = tid >> 8, f = tid & 255;
        size_t o = ((size_t)(conv * 256 + 2 * b)) * 256 + f;   // mb64 = 2b, 2b+1
        float a = af[tid], d = df[tid];
        float v;
        if (a >= 0.f) v = fmaxf(mxF[o], mxF[o + 256]);
        else          v = fminf(mnF[o], mnF[o + 256]);
        pl[tid] = fmaxf(a * v + d, 0.f);
    }
    __syncthreads();
    if (tid < 800) {
        int part = tid / 100, f = tid % 100;
        const float* pp = pl + part * 96;
        const float* wp = fc1w + (size_t)(part * 96) * 100 + f;
        float s = 0.f;
#pragma unroll 8
        for (int j = 0; j < 96; ++j) s += pp[j] * wp[(size_t)j * 100];
        ps[part][f] = s;
    }
    __syncthreads();
    if (tid < 100) {
        float s = fc1b[tid];
#pragma unroll
        for (int p = 0; p < 8; ++p) s += ps[p][tid];
        zb[b * 100 + tid] = s;
    }
}

// ---------------- 5. BN(batch) + relu + FC2 + softmax (1 block x 1024) ------
__global__ void fc2bn_kernel(const float* __restrict__ zb, const float* __restrict__ g1,
                             const float* __restrict__ b1, const float* __restrict__ fc2w,
                             const float* __restrict__ fc2b, float* __restrict__ out) {
    int tid = threadIdx.x;
    __shared__ float z[128][101];
    __shared__ float av[100], dv[100];
    __shared__ float w2s[100][10];
    __shared__ float sst[8][100], qst[8][100];
    __shared__ float lgs[128][12];
    for (int i = tid; i < 12800; i += 1024) z[i / 100][i % 100] = zb[i];
    for (int i = tid; i < 1000; i += 1024) (&w2s[0][0])[i] = fc2w[i];
    __syncthreads();
    if (tid < 800) {
        int col = tid % 100, part = tid / 100;
        float s = 0.f, q = 0.f;
#pragma unroll 4
        for (int r = part * 16; r < part * 16 + 16; ++r) {
            float v = z[r][col]; s += v; q += v * v;
        }
        sst[part][col] = s; qst[part][col] = q;
    }
    __syncthreads();
    if (tid < 100) {
        float s = 0.f, q = 0.f;
#pragma unroll
        for (int p = 0; p < 8; ++p) { s += sst[p][tid]; q += qst[p][tid]; }
        float mu = s / 128.f;
        float var = fmaxf(q / 128.f - mu * mu, 0.f);
        float a = g1[tid] * rsqrtf(var + 1e-5f);
        av[tid] = a; dv[tid] = b1[tid] - mu * a;
    }
    __syncthreads();
    if (tid < 640) {
        int r = tid / 5, cg = tid % 5;
        int c0 = 2 * cg, c1 = c0 + 1;
        float l0 = fc2b[c0], l1 = fc2b[c1];
        for (int j = 0; j < 100; ++j) {
            float v = fmaxf(av[j] * z[r][j] + dv[j], 0.f);
            l0 += v * w2s[j][c0]; l1 += v * w2s[j][c1];
        }
        lgs[r][c0] = l0; lgs[r][c1] = l1;
    }
    __syncthreads();
    if (tid < 128) {
        int r = tid;
        float m = lgs[r][0];
#pragma unroll
        for (int c = 1; c < 10; ++c) m = fmaxf(m, lgs[r][c]);
        float e[10], sum = 0.f;
#pragma unroll
        for (int c = 0; c < 10; ++c) { e[c] = expf(lgs[r][c] - m); sum += e[c]; }
#pragma unroll
        for (int c = 0; c < 10; ++c) out[r * 10 + c] = e[c] / sum;
    }
}

// ---------------- launch -----------------------------------------------------
extern "C" void kernel_launch(void* const* d_in, const int* in_sizes, int n_in,
                              void* d_out, int out_size, void* d_ws, size_t ws_size,
                              hipStream_t stream) {
    const float* x    = (const float*)d_in[0];
    const float* embw = (const float*)d_in[1];
    const float* cw0 = (const float*)d_in[2],  *cb0 = (const float*)d_in[3];
    const float* bg0 = (const float*)d_in[4],  *bb0 = (const float*)d_in[5];
    const float* cw1 = (const float*)d_in[6],  *cb1 = (const float*)d_in[7];
    const float* bg1 = (const float*)d_in[8],  *bb1 = (const float*)d_in[9];
    const float* cw2 = (const float*)d_in[10], *cb2 = (const float*)d_in[11];
    const float* bg2 = (const float*)d_in[12], *bb2 = (const float*)d_in[13];
    const float* fc1w = (const float*)d_in[14], *fc1b = (const float*)d_in[15];
    const float* g1   = (const float*)d_in[16], *b1   = (const float*)d_in[17];
    const float* fc2w = (const float*)d_in[18], *fc2b = (const float*)d_in[19];

    char* ws = (char*)d_ws;
    short* emb  = (short*)(ws);                    // 16,781,312 B
    short* Wtb  = (short*)(ws + 16781312);         //  2,359,296 B
    float* sumP = (float*)(ws + 19140608);         //    786,432 B each
    float* ssqP = (float*)(ws + 19927040);
    float* mxF  = (float*)(ws + 20713472);
    float* mnF  = (float*)(ws + 21499904);
    float* af   = (float*)(ws + 22286336);         //      3,072 B
    float* df   = (float*)(ws + 22289408);
    float* zb   = (float*)(ws + 22292480);         //     51,200 B  (end 22.34MB)

    embed_prep<<<PREPB + MPAD, 256, 0, stream>>>(x, embw, emb, cw0, cw1, cw2, Wtb);
    conv_gemm<<<1536, 256, 0, stream>>>(emb, Wtb, cb0, cb1, cb2,
                                        sumP, ssqP, mxF, mnF);
    bn_stats<<<3, 1024, 0, stream>>>(sumP, ssqP, bg0, bg1, bg2, bb0, bb1, bb2, af, df);
    pool_fc1<<<128, 1024, 0, stream>>>(mxF, mnF, af, df, fc1w, fc1b, zb);
    fc2bn_kernel<<<1, 1024, 0, stream>>>(zb, g1, b1, fc2w, fc2b, (float*)d_out);
}

// Round 16
// 98.263 us; speedup vs baseline: 1.1391x; 1.1391x over previous
//
#include <hip/hip_runtime.h>
#include <cstdint>
#include <cstddef>

#define MTOT 16384      // B*S
#define MPAD 16388      // + 4 zero pad rows
#define INCH 512        // W*E
#define NF   256        // filters per conv
#define PREPB 6144      // prep blocks (2048 per conv)

typedef __attribute__((ext_vector_type(4))) float f32x4;
typedef __attribute__((ext_vector_type(8))) short bf16x8;

__device__ __forceinline__ short f2bf(float f) {
    union { float f; unsigned u; } v; v.f = f;
    unsigned r = v.u + 0x7FFFu + ((v.u >> 16) & 1u);
    return (short)(r >> 16);
}

__device__ __forceinline__ void gld16(const short* g, short* l) {
    __builtin_amdgcn_global_load_lds(
        (const __attribute__((address_space(1))) unsigned int*)g,
        (__attribute__((address_space(3))) unsigned int*)l,
        16, 0, 0);
}

// ---------------- 1. fused: conv-weight prep + embedding gather -------------
// Weight layout (BK=32): [kt(k>>5)][nb][128 fr][4 cc][8 klo], cc = kc^((fr>>1)&3)
__global__ void embed_prep(const float* __restrict__ x, const float* __restrict__ ew,
                           short* __restrict__ emb,
                           const float* __restrict__ w0, const float* __restrict__ w1,
                           const float* __restrict__ w2, short* __restrict__ Wtb) {
    int tid = threadIdx.x;
    if (blockIdx.x < PREPB) {
        int blk = blockIdx.x;
        int conv = blk >> 11;
        int ki = conv + 2;
        int K = 512 * ki;
        int idx = (blk & 2047) * 256 + tid;
        if (idx >= K * NF) return;
        int u = idx >> 9;
        int ic = idx & 511;
        int f = u / ki;
        int j = u - f * ki;
        const float* w = (conv == 0) ? w0 : (conv == 1) ? w1 : w2;
        float val = w[(size_t)f * K + ic * ki + j];
        int k = j * 512 + ic;
        int kt = k >> 5, kl = k & 31;
        int kc = kl >> 3, klo = kl & 7;
        int nb = f >> 7, fr = f & 127;
        int cc = kc ^ ((fr >> 1) & 3);
        size_t off = (conv == 0) ? 0 : (conv == 1) ? 262144 : 655360;
        Wtb[off + (((size_t)(kt * 2 + nb) * 128 + fr) * 4 + cc) * 8 + klo] = f2bf(val);
        return;
    }
    int m = blockIdx.x - PREPB;
    if (m >= MTOT) {
        if (tid < 64) {
            uint4 z = make_uint4(0u, 0u, 0u, 0u);
            *(uint4*)&emb[(size_t)m * INCH + tid * 8] = z;
        }
        return;
    }
    int w = tid >> 4, u = tid & 15;
    const float* xr = x + ((size_t)m * 16 + w) * 128 + u * 8;
    float4 a0 = *(const float4*)xr;
    float4 a1 = *(const float4*)(xr + 4);
    float vals[8] = {a0.x, a0.y, a0.z, a0.w, a1.x, a1.y, a1.z, a1.w};
    int myidx = 0;
#pragma unroll
    for (int jj = 0; jj < 8; ++jj)
        if (vals[jj] != 0.f) myidx = u * 8 + jj;
#pragma unroll
    for (int off = 1; off < 16; off <<= 1)
        myidx = max(myidx, __shfl_xor(myidx, off));
    if (u < 4) {
        const float* er = ew + (size_t)myidx * 32 + u * 8;
        float4 e0 = *(const float4*)er;
        float4 e1 = *(const float4*)(er + 4);
        short h[8];
        h[0] = f2bf(e0.x); h[1] = f2bf(e0.y); h[2] = f2bf(e0.z); h[3] = f2bf(e0.w);
        h[4] = f2bf(e1.x); h[5] = f2bf(e1.y); h[6] = f2bf(e1.z); h[7] = f2bf(e1.w);
        *(uint4*)&emb[(size_t)m * INCH + w * 32 + u * 8] = *(uint4*)h;
    }
}

// ---------------- 2. conv GEMM: 256x128 tile, 8x4 register blocking ---------
// Per wave: 128 rows x 64 cols = 8 A-frags + 4 B-frags (12 ds_read_b128)
// feeding 32 MFMAs -> LDS-read/compute ratio 0.9 (was 1.2): compute-bound.
// M=256 = 2 batch rows; each wave owns one (brow, 64-col) stat set.
__launch_bounds__(256)
__global__ void conv_gemm(const short* __restrict__ emb, const short* __restrict__ Wtb,
                          const float* __restrict__ cb0, const float* __restrict__ cb1,
                          const float* __restrict__ cb2,
                          float* __restrict__ sumP, float* __restrict__ ssqP,
                          float* __restrict__ mxF, float* __restrict__ mnF) {
    // 384 blocks, 48/XCD; consecutive logicals mix (conv,nb) for balance.
    int o = blockIdx.x;
    int logical = (o & 7) * 48 + (o >> 3);
    int mb = logical / 6;            // 0..63 (256-row tiles)
    int r6 = logical - mb * 6;
    int conv = r6 >> 1;
    int nb = r6 & 1;
    int ki = conv + 2;
    int m0 = mb * 256;
    const short* Wc = Wtb + ((conv == 0) ? 0 : (conv == 1) ? 262144 : 655360);

    __shared__ __align__(16) short As[260 * 32];    // 16.25 KB (4 boundary rows)
    __shared__ __align__(16) short Bs[4 * 4096];    // 32 KB (4 j-slices)

    int tid = threadIdx.x;
    int wv = tid >> 6, lane = tid & 63, g = lane >> 4, ln = lane & 15;
    int wr = wv >> 1, wc = wv & 1;   // wave: rows [wr*128,+128), cols [wc*64,+64)

    f32x4 acc[8][4];
#pragma unroll
    for (int i = 0; i < 8; ++i)
#pragma unroll
        for (int n = 0; n < 4; ++n) acc[i][n] = (f32x4){0.f, 0.f, 0.f, 0.f};

    // A staging: 1040 chunks (260 rows x 4); thread chunks q*256+tid (q=0..3),
    // boundary chunks 1024..1039 (rows 256..259) via explicit load (tid<16).
    int arow[4], acol[4];
#pragma unroll
    for (int q = 0; q < 4; ++q) {
        int c = q * 256 + tid;
        arow[q] = c >> 2;
        acol[q] = ((c & 3) ^ ((arow[q] >> 1) & 3)) * 8;   // pre-swizzled source
    }
    int xrow = 256 + (tid >> 2);
    int xcol = ((tid & 3) ^ ((xrow >> 1) & 3)) * 8;
    int c0 = tid, c1 = 256 + tid;

    // B fragment offsets (per j-slice base added in loop)
    int bOff[4];
#pragma unroll
    for (int i = 0; i < 4; ++i) {
        int F = wc * 64 + i * 16 + ln;
        bOff[i] = F * 32 + ((g ^ ((F >> 1) & 3)) * 8);
    }
    int Ra = wr * 128 + ln;          // A row base for mi=0, jj=0

    for (int ic0 = 0; ic0 < INCH; ic0 += 32) {
        int kt0 = ic0 >> 5;
        const short* abase = emb + (size_t)m0 * INCH + ic0;
        __syncthreads();                      // prior compute done: buffers free
#pragma unroll
        for (int q = 0; q < 4; ++q)
            gld16(abase + (size_t)arow[q] * INCH + acol[q], As + q * 2048 + wv * 512);
        if (tid < 16) {                       // boundary rows 256..259
            bf16x8 v = *(const bf16x8*)&abase[(size_t)xrow * INCH + xcol];
            *(bf16x8*)&As[(1024 + tid) * 8] = v;
        }
        for (int jj = 0; jj < ki; ++jj) {
            const short* Bsrc = Wc + (size_t)((jj * 16 + kt0) * 2 + nb) * 4096;
            gld16(Bsrc + c0 * 8, Bs + jj * 4096 + wv * 512);
            gld16(Bsrc + c1 * 8, Bs + jj * 4096 + 2048 + wv * 512);
        }
        __syncthreads();                      // staged data visible
        for (int jj = 0; jj < ki; ++jj) {
            bf16x8 afr[8], bfr[4];
#pragma unroll
            for (int mi = 0; mi < 8; ++mi) {
                int R = Ra + mi * 16 + jj;
                afr[mi] = *(const bf16x8*)&As[R * 32 + ((g ^ ((R >> 1) & 3)) * 8)];
            }
#pragma unroll
            for (int i = 0; i < 4; ++i) bfr[i] = *(const bf16x8*)&Bs[jj * 4096 + bOff[i]];
#pragma unroll
            for (int mi = 0; mi < 8; ++mi)
#pragma unroll
                for (int ni = 0; ni < 4; ++ni)
                    acc[mi][ni] = __builtin_amdgcn_mfma_f32_16x16x32_bf16(afr[mi], bfr[ni], acc[mi][ni], 0, 0, 0);
        }
    }

    // epilogue: bias + {sum,sumsq,max,min}; wave owns (brow = 2mb+wr, 64 cols)
    int L = 127 - conv;
    int brow = 2 * mb + wr;
    const float* cbp = (conv == 0) ? cb0 : (conv == 1) ? cb1 : cb2;
    float s[4] = {0.f, 0.f, 0.f, 0.f}, q[4] = {0.f, 0.f, 0.f, 0.f};
    float mx[4], mn[4], cb[4];
#pragma unroll
    for (int ni = 0; ni < 4; ++ni) {
        mx[ni] = -3.0e38f; mn[ni] = 3.0e38f;
        cb[ni] = cbp[nb * 128 + wc * 64 + ni * 16 + ln];
    }
#pragma unroll
    for (int mi = 0; mi < 8; ++mi) {
#pragma unroll
        for (int r = 0; r < 4; ++r) {
            int t = mi * 16 + g * 4 + r;       // t within batch row
            if (t >= L) continue;
#pragma unroll
            for (int ni = 0; ni < 4; ++ni) {
                float c = acc[mi][ni][r] + cb[ni];
                s[ni] += c; q[ni] += c * c;
                mx[ni] = fmaxf(mx[ni], c); mn[ni] = fminf(mn[ni], c);
            }
        }
    }
#pragma unroll
    for (int off = 16; off < 64; off <<= 1) {
#pragma unroll
        for (int ni = 0; ni < 4; ++ni) {
            s[ni] += __shfl_xor(s[ni], off);
            q[ni] += __shfl_xor(q[ni], off);
            mx[ni] = fmaxf(mx[ni], __shfl_xor(mx[ni], off));
            mn[ni] = fminf(mn[ni], __shfl_xor(mn[ni], off));
        }
    }
    if (g == 0) {                              // lanes 0..15: direct store
#pragma unroll
        for (int ni = 0; ni < 4; ++ni) {
            int col = nb * 128 + wc * 64 + ni * 16 + ln;
            size_t off2 = ((size_t)(conv * 128 + brow)) * 256 + col;
            sumP[off2] = s[ni]; ssqP[off2] = q[ni];
            mxF[off2] = mx[ni]; mnF[off2] = mn[ni];
        }
    }
}

// ---------------- 3. BN stats only: af/df[768] (3 blocks x 1024) ------------
__global__ void bn_stats(const float* __restrict__ sumP, const float* __restrict__ ssqP,
                         const float* __restrict__ g0, const float* __restrict__ g1,
                         const float* __restrict__ g2,
                         const float* __restrict__ b0, const float* __restrict__ b1,
                         const float* __restrict__ b2,
                         float* __restrict__ af, float* __restrict__ df) {
    int conv = blockIdx.x;
    int tid = threadIdx.x;
    int part = tid >> 8, f = tid & 255;
    float s = 0.f, q = 0.f;
#pragma unroll 4
    for (int mb = part * 32; mb < part * 32 + 32; ++mb) {
        size_t o = ((size_t)(conv * 128 + mb)) * 256 + f;
        s += sumP[o]; q += ssqP[o];
    }
    __shared__ float sred[4][256], qred[4][256];
    sred[part][f] = s; qred[part][f] = q;
    __syncthreads();
    if (part == 0) {
        s = sred[0][f] + sred[1][f] + sred[2][f] + sred[3][f];
        q = qred[0][f] + qred[1][f] + qred[2][f] + qred[3][f];
        int L = 127 - conv;
        float n = 128.f * (float)L;
        float mu = s / n;
        float var = fmaxf(q / n - mu * mu, 0.f);
        const float* gp = (conv == 0) ? g0 : (conv == 1) ? g1 : g2;
        const float* bp = (conv == 0) ? b0 : (conv == 1) ? b1 : b2;
        float a = gp[f] * rsqrtf(var + 1e-5f);
        af[conv * 256 + f] = a;
        df[conv * 256 + f] = bp[f] - mu * a;
    }
}

// ---------------- 4. pool + FC1: 128 blocks x 1024 threads ------------------
__global__ void pool_fc1(const float* __restrict__ mxF, const float* __restrict__ mnF,
                         const float* __restrict__ af, const float* __restrict__ df,
                         const float* __restrict__ fc1w, const float* __restrict__ fc1b,
                         float* __restrict__ zb) {
    int b = blockIdx.x;
    int tid = threadIdx.x;
    __shared__ float pl[768];
    __shared__ float ps[8][100];
    if (tid < 768) {
        int conv = tid >> 8, f = tid & 255;
        size_t o = ((size_t)(conv * 128 + b)) * 256 + f;
        float a = af[tid], d = df[tid];
        float v = (a >= 0.f) ? mxF[o] : mnF[o];
        pl[tid] = fmaxf(a * v + d, 0.f);
    }
    __syncthreads();
    if (tid < 800) {
        int part = tid / 100, f = tid % 100;
        const float* pp = pl + part * 96;
        const float* wp = fc1w + (size_t)(part * 96) * 100 + f;
        float s = 0.f;
#pragma unroll 8
        for (int j = 0; j < 96; ++j) s += pp[j] * wp[(size_t)j * 100];
        ps[part][f] = s;
    }
    __syncthreads();
    if (tid < 100) {
        float s = fc1b[tid];
#pragma unroll
        for (int p = 0; p < 8; ++p) s += ps[p][tid];
        zb[b * 100 + tid] = s;
    }
}

// ---------------- 5. BN(batch) + relu + FC2 + softmax (1 block x 1024) ------
__global__ void fc2bn_kernel(const float* __restrict__ zb, const float* __restrict__ g1,
                             const float* __restrict__ b1, const float* __restrict__ fc2w,
                             const float* __restrict__ fc2b, float* __restrict__ out) {
    int tid = threadIdx.x;
    __shared__ float z[128][101];
    __shared__ float av[100], dv[100];
    __shared__ float w2s[100][10];
    __shared__ float sst[8][100], qst[8][100];
    __shared__ float lgs[128][12];
    for (int i = tid; i < 12800; i += 1024) z[i / 100][i % 100] = zb[i];
    for (int i = tid; i < 1000; i += 1024) (&w2s[0][0])[i] = fc2w[i];
    __syncthreads();
    if (tid < 800) {
        int col = tid % 100, part = tid / 100;
        float s = 0.f, q = 0.f;
#pragma unroll 4
        for (int r = part * 16; r < part * 16 + 16; ++r) {
            float v = z[r][col]; s += v; q += v * v;
        }
        sst[part][col] = s; qst[part][col] = q;
    }
    __syncthreads();
    if (tid < 100) {
        float s = 0.f, q = 0.f;
#pragma unroll
        for (int p = 0; p < 8; ++p) { s += sst[p][tid]; q += qst[p][tid]; }
        float mu = s / 128.f;
        float var = fmaxf(q / 128.f - mu * mu, 0.f);
        float a = g1[tid] * rsqrtf(var + 1e-5f);
        av[tid] = a; dv[tid] = b1[tid] - mu * a;
    }
    __syncthreads();
    if (tid < 640) {
        int r = tid / 5, cg = tid % 5;
        int c0 = 2 * cg, c1 = c0 + 1;
        float l0 = fc2b[c0], l1 = fc2b[c1];
        for (int j = 0; j < 100; ++j) {
            float v = fmaxf(av[j] * z[r][j] + dv[j], 0.f);
            l0 += v * w2s[j][c0]; l1 += v * w2s[j][c1];
        }
        lgs[r][c0] = l0; lgs[r][c1] = l1;
    }
    __syncthreads();
    if (tid < 128) {
        int r = tid;
        float m = lgs[r][0];
#pragma unroll
        for (int c = 1; c < 10; ++c) m = fmaxf(m, lgs[r][c]);
        float e[10], sum = 0.f;
#pragma unroll
        for (int c = 0; c < 10; ++c) { e[c] = expf(lgs[r][c] - m); sum += e[c]; }
#pragma unroll
        for (int c = 0; c < 10; ++c) out[r * 10 + c] = e[c] / sum;
    }
}

// ---------------- launch -----------------------------------------------------
extern "C" void kernel_launch(void* const* d_in, const int* in_sizes, int n_in,
                              void* d_out, int out_size, void* d_ws, size_t ws_size,
                              hipStream_t stream) {
    const float* x    = (const float*)d_in[0];
    const float* embw = (const float*)d_in[1];
    const float* cw0 = (const float*)d_in[2],  *cb0 = (const float*)d_in[3];
    const float* bg0 = (const float*)d_in[4],  *bb0 = (const float*)d_in[5];
    const float* cw1 = (const float*)d_in[6],  *cb1 = (const float*)d_in[7];
    const float* bg1 = (const float*)d_in[8],  *bb1 = (const float*)d_in[9];
    const float* cw2 = (const float*)d_in[10], *cb2 = (const float*)d_in[11];
    const float* bg2 = (const float*)d_in[12], *bb2 = (const float*)d_in[13];
    const float* fc1w = (const float*)d_in[14], *fc1b = (const float*)d_in[15];
    const float* g1   = (const float*)d_in[16], *b1   = (const float*)d_in[17];
    const float* fc2w = (const float*)d_in[18], *fc2b = (const float*)d_in[19];

    char* ws = (char*)d_ws;
    short* emb  = (short*)(ws);                    // 16,781,312 B
    short* Wtb  = (short*)(ws + 16781312);         //  2,359,296 B
    float* sumP = (float*)(ws + 19140608);         //    393,216 B each
    float* ssqP = (float*)(ws + 19533824);
    float* mxF  = (float*)(ws + 19927040);
    float* mnF  = (float*)(ws + 20320256);
    float* af   = (float*)(ws + 20713472);         //      3,072 B
    float* df   = (float*)(ws + 20716544);
    float* zb   = (float*)(ws + 20719616);         //     51,200 B

    embed_prep<<<PREPB + MPAD, 256, 0, stream>>>(x, embw, emb, cw0, cw1, cw2, Wtb);
    conv_gemm<<<384, 256, 0, stream>>>(emb, Wtb, cb0, cb1, cb2,
                                       sumP, ssqP, mxF, mnF);
    bn_stats<<<3, 1024, 0, stream>>>(sumP, ssqP, bg0, bg1, bg2, bb0, bb1, bb2, af, df);
    pool_fc1<<<128, 1024, 0, stream>>>(mxF, mnF, af, df, fc1w, fc1b, zb);
    fc2bn_kernel<<<1, 1024, 0, stream>>>(zb, g1, b1, fc2w, fc2b, (float*)d_out);
}

// Round 17
// 92.604 us; speedup vs baseline: 1.2088x; 1.0611x over previous
//
#include <hip/hip_runtime.h>
#include <cstdint>
#include <cstddef>

#define MTOT 16384      // B*S
#define MPAD 16388      // + 4 zero pad rows
#define INCH 512        // W*E
#define NF   256        // filters per conv
#define PREPB 6144      // prep blocks (2048 per conv)

typedef __attribute__((ext_vector_type(4))) float f32x4;
typedef __attribute__((ext_vector_type(8))) short bf16x8;

__device__ __forceinline__ short f2bf(float f) {
    union { float f; unsigned u; } v; v.f = f;
    unsigned r = v.u + 0x7FFFu + ((v.u >> 16) & 1u);
    return (short)(r >> 16);
}

__device__ __forceinline__ void gld16(const short* g, short* l) {
    __builtin_amdgcn_global_load_lds(
        (const __attribute__((address_space(1))) unsigned int*)g,
        (__attribute__((address_space(3))) unsigned int*)l,
        16, 0, 0);
}

// ---------------- 1. fused: conv-weight prep + embedding gather -------------
// Weight layout (BK=32): [kt(k>>5)][nb][128 fr][4 cc][8 klo], cc = kc^((fr>>1)&3)
__global__ void embed_prep(const float* __restrict__ x, const float* __restrict__ ew,
                           short* __restrict__ emb,
                           const float* __restrict__ w0, const float* __restrict__ w1,
                           const float* __restrict__ w2, short* __restrict__ Wtb) {
    int tid = threadIdx.x;
    if (blockIdx.x < PREPB) {
        int blk = blockIdx.x;
        int conv = blk >> 11;
        int ki = conv + 2;
        int K = 512 * ki;
        int idx = (blk & 2047) * 256 + tid;
        if (idx >= K * NF) return;
        int u = idx >> 9;
        int ic = idx & 511;
        int f = u / ki;
        int j = u - f * ki;
        const float* w = (conv == 0) ? w0 : (conv == 1) ? w1 : w2;
        float val = w[(size_t)f * K + ic * ki + j];
        int k = j * 512 + ic;
        int kt = k >> 5, kl = k & 31;
        int kc = kl >> 3, klo = kl & 7;
        int nb = f >> 7, fr = f & 127;
        int cc = kc ^ ((fr >> 1) & 3);
        size_t off = (conv == 0) ? 0 : (conv == 1) ? 262144 : 655360;
        Wtb[off + (((size_t)(kt * 2 + nb) * 128 + fr) * 4 + cc) * 8 + klo] = f2bf(val);
        return;
    }
    int m = blockIdx.x - PREPB;
    if (m >= MTOT) {
        if (tid < 64) {
            uint4 z = make_uint4(0u, 0u, 0u, 0u);
            *(uint4*)&emb[(size_t)m * INCH + tid * 8] = z;
        }
        return;
    }
    int w = tid >> 4, u = tid & 15;
    const float* xr = x + ((size_t)m * 16 + w) * 128 + u * 8;
    float4 a0 = *(const float4*)xr;
    float4 a1 = *(const float4*)(xr + 4);
    float vals[8] = {a0.x, a0.y, a0.z, a0.w, a1.x, a1.y, a1.z, a1.w};
    int myidx = 0;
#pragma unroll
    for (int jj = 0; jj < 8; ++jj)
        if (vals[jj] != 0.f) myidx = u * 8 + jj;
#pragma unroll
    for (int off = 1; off < 16; off <<= 1)
        myidx = max(myidx, __shfl_xor(myidx, off));
    if (u < 4) {
        const float* er = ew + (size_t)myidx * 32 + u * 8;
        float4 e0 = *(const float4*)er;
        float4 e1 = *(const float4*)(er + 4);
        short h[8];
        h[0] = f2bf(e0.x); h[1] = f2bf(e0.y); h[2] = f2bf(e0.z); h[3] = f2bf(e0.w);
        h[4] = f2bf(e1.x); h[5] = f2bf(e1.y); h[6] = f2bf(e1.z); h[7] = f2bf(e1.w);
        *(uint4*)&emb[(size_t)m * INCH + w * 32 + u * 8] = *(uint4*)h;
    }
}

// ---------------- 2. conv GEMM: BK=32, A staged once, j-shift in LDS reads --
// Measured best (R14, 92.6us total): 1 drain per ki*16 MFMAs/wave.
__launch_bounds__(256)
__global__ void conv_gemm(const short* __restrict__ emb, const short* __restrict__ Wtb,
                          const float* __restrict__ cb0, const float* __restrict__ cb1,
                          const float* __restrict__ cb2,
                          float* __restrict__ sumP, float* __restrict__ ssqP,
                          float* __restrict__ mxF, float* __restrict__ mnF) {
    int o = blockIdx.x;
    int logical = (o & 7) * 96 + (o >> 3);
    int mb = logical / 6;
    int r6 = logical - mb * 6;
    int conv = r6 >> 1;
    int nb = r6 & 1;
    int ki = conv + 2;
    int m0 = mb * 128;
    const short* Wc = Wtb + ((conv == 0) ? 0 : (conv == 1) ? 262144 : 655360);

    __shared__ __align__(16) short As[132 * 32];    // 8.25 KB (132 rows)
    __shared__ __align__(16) short Bs[4 * 4096];    // 32 KB (4 j-slices)

    int tid = threadIdx.x;
    int wv = tid >> 6, lane = tid & 63, g = lane >> 4, ln = lane & 15;
    int wr = wv >> 1, wc = wv & 1;

    f32x4 acc[4][4];
#pragma unroll
    for (int i = 0; i < 4; ++i)
#pragma unroll
        for (int n = 0; n < 4; ++n) acc[i][n] = (f32x4){0.f, 0.f, 0.f, 0.f};

    int arow0 = tid >> 2, acol0 = (((tid)&3) ^ ((arow0 >> 1) & 3)) * 8;
    int arow1 = (256 + tid) >> 2, acol1 = (((256 + tid) & 3) ^ ((arow1 >> 1) & 3)) * 8;
    int xrow = 128 + (tid >> 2);
    int xcol = (((tid) & 3) ^ ((xrow >> 1) & 3)) * 8;
    int c0 = tid, c1 = 256 + tid;

    int bOff[4];
#pragma unroll
    for (int i = 0; i < 4; ++i) {
        int F = wc * 64 + i * 16 + ln;
        bOff[i] = F * 32 + ((g ^ ((F >> 1) & 3)) * 8);
    }
    int Rb[4];
#pragma unroll
    for (int i = 0; i < 4; ++i) Rb[i] = wr * 64 + i * 16 + ln;

    for (int ic0 = 0; ic0 < INCH; ic0 += 32) {
        int kt0 = ic0 >> 5;
        const short* abase = emb + (size_t)m0 * INCH + ic0;
        __syncthreads();                      // prior compute done: buffers free
        gld16(abase + (size_t)arow0 * INCH + acol0, As + wv * 512);
        gld16(abase + (size_t)arow1 * INCH + acol1, As + 2048 + wv * 512);
        if (tid < 16) {                       // boundary rows 128..131
            bf16x8 v = *(const bf16x8*)&abase[(size_t)xrow * INCH + xcol];
            *(bf16x8*)&As[(512 + tid) * 8] = v;
        }
        for (int jj = 0; jj < ki; ++jj) {
            const short* Bsrc = Wc + (size_t)((jj * 16 + kt0) * 2 + nb) * 4096;
            gld16(Bsrc + c0 * 8, Bs + jj * 4096 + wv * 512);
            gld16(Bsrc + c1 * 8, Bs + jj * 4096 + 2048 + wv * 512);
        }
        __syncthreads();                      // staged data visible
        for (int jj = 0; jj < ki; ++jj) {
            bf16x8 afr[4], bfr[4];
#pragma unroll
            for (int i = 0; i < 4; ++i) {
                int Rj = Rb[i] + jj;
                afr[i] = *(const bf16x8*)&As[Rj * 32 + ((g ^ ((Rj >> 1) & 3)) * 8)];
            }
#pragma unroll
            for (int i = 0; i < 4; ++i) bfr[i] = *(const bf16x8*)&Bs[jj * 4096 + bOff[i]];
#pragma unroll
            for (int mi = 0; mi < 4; ++mi)
#pragma unroll
                for (int ni = 0; ni < 4; ++ni)
                    acc[mi][ni] = __builtin_amdgcn_mfma_f32_16x16x32_bf16(afr[mi], bfr[ni], acc[mi][ni], 0, 0, 0);
        }
    }

    // epilogue: bias + per-(b,f) {sum, sumsq, max, min}; block row = batch b
    int L = 127 - conv;
    const float* cbp = (conv == 0) ? cb0 : (conv == 1) ? cb1 : cb2;
    float s[4] = {0.f, 0.f, 0.f, 0.f}, q[4] = {0.f, 0.f, 0.f, 0.f};
    float mx[4], mn[4], cb[4];
#pragma unroll
    for (int ni = 0; ni < 4; ++ni) {
        mx[ni] = -3.0e38f; mn[ni] = 3.0e38f;
        cb[ni] = cbp[nb * 128 + wc * 64 + ni * 16 + ln];
    }
#pragma unroll
    for (int mi = 0; mi < 4; ++mi) {
#pragma unroll
        for (int r = 0; r < 4; ++r) {
            int t = wr * 64 + mi * 16 + g * 4 + r;
            if (t >= L) continue;
#pragma unroll
            for (int ni = 0; ni < 4; ++ni) {
                float c = acc[mi][ni][r] + cb[ni];
                s[ni] += c; q[ni] += c * c;
                mx[ni] = fmaxf(mx[ni], c); mn[ni] = fminf(mn[ni], c);
            }
        }
    }
#pragma unroll
    for (int off = 16; off < 64; off <<= 1) {
#pragma unroll
        for (int ni = 0; ni < 4; ++ni) {
            s[ni] += __shfl_xor(s[ni], off);
            q[ni] += __shfl_xor(q[ni], off);
            mx[ni] = fmaxf(mx[ni], __shfl_xor(mx[ni], off));
            mn[ni] = fminf(mn[ni], __shfl_xor(mn[ni], off));
        }
    }
    __syncthreads();
    float* sm = (float*)As;
    if (g == 0) {
#pragma unroll
        for (int ni = 0; ni < 4; ++ni) {
            int col = wc * 64 + ni * 16 + ln;
            int oo = wr * 128 + col;
            sm[oo] = s[ni]; sm[256 + oo] = q[ni];
            sm[512 + oo] = mx[ni]; sm[768 + oo] = mn[ni];
        }
    }
    __syncthreads();
    if (tid < 128) {
        float S  = sm[tid] + sm[128 + tid];
        float Q  = sm[256 + tid] + sm[384 + tid];
        float MX = fmaxf(sm[512 + tid], sm[640 + tid]);
        float MN = fminf(sm[768 + tid], sm[896 + tid]);
        size_t off2 = ((size_t)(conv * 128 + mb)) * 256 + nb * 128 + tid;
        sumP[off2] = S; ssqP[off2] = Q; mxF[off2] = MX; mnF[off2] = MN;
    }
}

// ---------------- 3. BN stats only: af/df[768] (3 blocks x 1024) ------------
__global__ void bn_stats(const float* __restrict__ sumP, const float* __restrict__ ssqP,
                         const float* __restrict__ g0, const float* __restrict__ g1,
                         const float* __restrict__ g2,
                         const float* __restrict__ b0, const float* __restrict__ b1,
                         const float* __restrict__ b2,
                         float* __restrict__ af, float* __restrict__ df) {
    int conv = blockIdx.x;
    int tid = threadIdx.x;
    int part = tid >> 8, f = tid & 255;
    float s = 0.f, q = 0.f;
#pragma unroll 4
    for (int mb = part * 32; mb < part * 32 + 32; ++mb) {
        size_t o = ((size_t)(conv * 128 + mb)) * 256 + f;
        s += sumP[o]; q += ssqP[o];
    }
    __shared__ float sred[4][256], qred[4][256];
    sred[part][f] = s; qred[part][f] = q;
    __syncthreads();
    if (part == 0) {
        s = sred[0][f] + sred[1][f] + sred[2][f] + sred[3][f];
        q = qred[0][f] + qred[1][f] + qred[2][f] + qred[3][f];
        int L = 127 - conv;
        float n = 128.f * (float)L;
        float mu = s / n;
        float var = fmaxf(q / n - mu * mu, 0.f);
        const float* gp = (conv == 0) ? g0 : (conv == 1) ? g1 : g2;
        const float* bp = (conv == 0) ? b0 : (conv == 1) ? b1 : b2;
        float a = gp[f] * rsqrtf(var + 1e-5f);
        af[conv * 256 + f] = a;
        df[conv * 256 + f] = bp[f] - mu * a;
    }
}

// ---------------- 4. pool + FC1: 128 blocks x 1024 threads ------------------
__global__ void pool_fc1(const float* __restrict__ mxF, const float* __restrict__ mnF,
                         const float* __restrict__ af, const float* __restrict__ df,
                         const float* __restrict__ fc1w, const float* __restrict__ fc1b,
                         float* __restrict__ zb) {
    int b = blockIdx.x;
    int tid = threadIdx.x;
    __shared__ float pl[768];
    __shared__ float ps[8][100];
    if (tid < 768) {
        int conv = tid >> 8, f = tid & 255;
        size_t o = ((size_t)(conv * 128 + b)) * 256 + f;
        float a = af[tid], d = df[tid];
        float v = (a >= 0.f) ? mxF[o] : mnF[o];
        pl[tid] = fmaxf(a * v + d, 0.f);
    }
    __syncthreads();
    if (tid < 800) {
        int part = tid / 100, f = tid % 100;
        const float* pp = pl + part * 96;
        const float* wp = fc1w + (size_t)(part * 96) * 100 + f;
        float s = 0.f;
#pragma unroll 8
        for (int j = 0; j < 96; ++j) s += pp[j] * wp[(size_t)j * 100];
        ps[part][f] = s;
    }
    __syncthreads();
    if (tid < 100) {
        float s = fc1b[tid];
#pragma unroll
        for (int p = 0; p < 8; ++p) s += ps[p][tid];
        zb[b * 100 + tid] = s;
    }
}

// ---------------- 5. BN(batch) + relu + FC2 + softmax (1 block x 1024) ------
__global__ void fc2bn_kernel(const float* __restrict__ zb, const float* __restrict__ g1,
                             const float* __restrict__ b1, const float* __restrict__ fc2w,
                             const float* __restrict__ fc2b, float* __restrict__ out) {
    int tid = threadIdx.x;
    __shared__ float z[128][101];
    __shared__ float av[100], dv[100];
    __shared__ float w2s[100][10];
    __shared__ float sst[8][100], qst[8][100];
    __shared__ float lgs[128][12];
    for (int i = tid; i < 12800; i += 1024) z[i / 100][i % 100] = zb[i];
    for (int i = tid; i < 1000; i += 1024) (&w2s[0][0])[i] = fc2w[i];
    __syncthreads();
    if (tid < 800) {
        int col = tid % 100, part = tid / 100;
        float s = 0.f, q = 0.f;
#pragma unroll 4
        for (int r = part * 16; r < part * 16 + 16; ++r) {
            float v = z[r][col]; s += v; q += v * v;
        }
        sst[part][col] = s; qst[part][col] = q;
    }
    __syncthreads();
    if (tid < 100) {
        float s = 0.f, q = 0.f;
#pragma unroll
        for (int p = 0; p < 8; ++p) { s += sst[p][tid]; q += qst[p][tid]; }
        float mu = s / 128.f;
        float var = fmaxf(q / 128.f - mu * mu, 0.f);
        float a = g1[tid] * rsqrtf(var + 1e-5f);
        av[tid] = a; dv[tid] = b1[tid] - mu * a;
    }
    __syncthreads();
    if (tid < 640) {
        int r = tid / 5, cg = tid % 5;
        int c0 = 2 * cg, c1 = c0 + 1;
        float l0 = fc2b[c0], l1 = fc2b[c1];
        for (int j = 0; j < 100; ++j) {
            float v = fmaxf(av[j] * z[r][j] + dv[j], 0.f);
            l0 += v * w2s[j][c0]; l1 += v * w2s[j][c1];
        }
        lgs[r][c0] = l0; lgs[r][c1] = l1;
    }
    __syncthreads();
    if (tid < 128) {
        int r = tid;
        float m = lgs[r][0];
#pragma unroll
        for (int c = 1; c < 10; ++c) m = fmaxf(m, lgs[r][c]);
        float e[10], sum = 0.f;
#pragma unroll
        for (int c = 0; c < 10; ++c) { e[c] = expf(lgs[r][c] - m); sum += e[c]; }
#pragma unroll
        for (int c = 0; c < 10; ++c) out[r * 10 + c] = e[c] / sum;
    }
}

// ---------------- launch -----------------------------------------------------
extern "C" void kernel_launch(void* const* d_in, const int* in_sizes, int n_in,
                              void* d_out, int out_size, void* d_ws, size_t ws_size,
                              hipStream_t stream) {
    const float* x    = (const float*)d_in[0];
    const float* embw = (const float*)d_in[1];
    const float* cw0 = (const float*)d_in[2],  *cb0 = (const float*)d_in[3];
    const float* bg0 = (const float*)d_in[4],  *bb0 = (const float*)d_in[5];
    const float* cw1 = (const float*)d_in[6],  *cb1 = (const float*)d_in[7];
    const float* bg1 = (const float*)d_in[8],  *bb1 = (const float*)d_in[9];
    const float* cw2 = (const float*)d_in[10], *cb2 = (const float*)d_in[11];
    const float* bg2 = (const float*)d_in[12], *bb2 = (const float*)d_in[13];
    const float* fc1w = (const float*)d_in[14], *fc1b = (const float*)d_in[15];
    const float* g1   = (const float*)d_in[16], *b1   = (const float*)d_in[17];
    const float* fc2w = (const float*)d_in[18], *fc2b = (const float*)d_in[19];

    char* ws = (char*)d_ws;
    short* emb  = (short*)(ws);
    short* Wtb  = (short*)(ws + 16781312);
    float* sumP = (float*)(ws + 19140608);
    float* ssqP = (float*)(ws + 19533824);
    float* mxF  = (float*)(ws + 19927040);
    float* mnF  = (float*)(ws + 20320256);
    float* af   = (float*)(ws + 20713472);
    float* df   = (float*)(ws + 20716544);
    float* zb   = (float*)(ws + 20719616);

    embed_prep<<<PREPB + MPAD, 256, 0, stream>>>(x, embw, emb, cw0, cw1, cw2, Wtb);
    conv_gemm<<<768, 256, 0, stream>>>(emb, Wtb, cb0, cb1, cb2,
                                       sumP, ssqP, mxF, mnF);
    bn_stats<<<3, 1024, 0, stream>>>(sumP, ssqP, bg0, bg1, bg2, bb0, bb1, bb2, af, df);
    pool_fc1<<<128, 1024, 0, stream>>>(mxF, mnF, af, df, fc1w, fc1b, zb);
    fc2bn_kernel<<<1, 1024, 0, stream>>>(zb, g1, b1, fc2w, fc2b, (float*)d_out);
}